// Round 10
// baseline (356.278 us; speedup 1.0000x reference)
//
#include <hip/hip_runtime.h>

#define DIM 64
#define PRESERVE 0.1f
#define SCHUNK 1024  // elements per scan chunk (256 thr x 4)

typedef unsigned short bf16_t;

__device__ __forceinline__ float readlane_f(float v, int l) {
    return __int_as_float(__builtin_amdgcn_readlane(__float_as_int(v), l));
}
__device__ __forceinline__ float bf2f(bf16_t u) {
    return __uint_as_float(((unsigned)u) << 16);
}
__device__ __forceinline__ bf16_t f2bf(float f) {
    unsigned u = __float_as_uint(f);
    unsigned r = (u + 0x7FFFu + ((u >> 16) & 1u)) >> 16;  // RNE
    return (bf16_t)r;
}

// ---------- FUSED: histogram+rank (first Gh blocks) || temp = x@W1 fp32 (rest) ----------
// hist is atomic-throughput-bound (VALUBusy ~0.3%): mm rides the idle VALU pipes.
__global__ __launch_bounds__(256) void k_hist_mm(
        const int* __restrict__ col, int* __restrict__ cursor,
        int* __restrict__ rank, int E,
        const float* __restrict__ x, const float* __restrict__ W,
        float* __restrict__ temp, int n) {
    const int G = gridDim.x;
    const int Gh = G / 3;
    const int bid = blockIdx.x;
    const int tid = threadIdx.x;
    if (bid < Gh) {
        // ---- hist role ----
        int t0 = bid * 256 + tid;
        int nh = Gh * 256;
        int nvec = E >> 2;
        const int4* col4 = (const int4*)col;
        int4* rank4 = (int4*)rank;
        for (int t = t0; t < nvec; t += nh) {
            int4 c = col4[t];
            int4 r;
            r.x = atomicAdd(&cursor[c.x], 1);
            r.y = atomicAdd(&cursor[c.y], 1);
            r.z = atomicAdd(&cursor[c.z], 1);
            r.w = atomicAdd(&cursor[c.w], 1);
            rank4[t] = r;
        }
        for (int e = (nvec << 2) + t0; e < E; e += nh)
            rank[e] = atomicAdd(&cursor[col[e]], 1);
    } else {
        // ---- mm role: temp = x @ W1 (fp32, unscaled) ----
        int mb = bid - Gh;
        int nmb = G - Gh;
        int lane = tid & 63;
        int waveId = mb * 4 + (tid >> 6);
        int nWaves = nmb * 4;
        float Wr[DIM];
#pragma unroll
        for (int k = 0; k < DIM; ++k) Wr[k] = W[k * DIM + lane];
        for (int r0 = waveId * 4; r0 < n; r0 += nWaves * 4) {
            if (r0 + 3 < n) {
                float x0 = x[(size_t)(r0 + 0) * DIM + lane];
                float x1 = x[(size_t)(r0 + 1) * DIM + lane];
                float x2 = x[(size_t)(r0 + 2) * DIM + lane];
                float x3 = x[(size_t)(r0 + 3) * DIM + lane];
                float a0 = 0.f, a1 = 0.f, a2 = 0.f, a3 = 0.f;
#pragma unroll
                for (int k = 0; k < DIM; ++k) {
                    float w = Wr[k];
                    a0 += readlane_f(x0, k) * w;
                    a1 += readlane_f(x1, k) * w;
                    a2 += readlane_f(x2, k) * w;
                    a3 += readlane_f(x3, k) * w;
                }
                temp[(size_t)(r0 + 0) * DIM + lane] = a0;
                temp[(size_t)(r0 + 1) * DIM + lane] = a1;
                temp[(size_t)(r0 + 2) * DIM + lane] = a2;
                temp[(size_t)(r0 + 3) * DIM + lane] = a3;
            } else {
                for (int r = r0; r < n; ++r) {
                    float xv = x[(size_t)r * DIM + lane];
                    float a = 0.f;
#pragma unroll
                    for (int k = 0; k < DIM; ++k) a += readlane_f(xv, k) * Wr[k];
                    temp[(size_t)r * DIM + lane] = a;
                }
            }
        }
    }
}

// ---------- single-launch decoupled-lookback exclusive scan ----------
// state[ch] packed: (flag<<30)|value, flag 1=aggregate 2=inclusive prefix. E<2^30.
// blockIdx == chunk id; nch (~98) blocks all resident at once -> lookback can't deadlock.
__global__ __launch_bounds__(256) void k_scan_lb(
        const int* __restrict__ cursor, int* __restrict__ offsets,
        unsigned int* __restrict__ state, int N, int E, int nch) {
    __shared__ int s[256];
    __shared__ int s_run;
    const int ch = blockIdx.x;
    const int tid = threadIdx.x;
    const int base = ch * SCHUNK + tid * 4;

    int a0 = 0, a1 = 0, a2 = 0, a3 = 0;
    if (base + 3 < N) {
        int4 v = *(const int4*)(cursor + base);
        a0 = v.x; a1 = v.y; a2 = v.z; a3 = v.w;
    } else {
        if (base < N) a0 = cursor[base];
        if (base + 1 < N) a1 = cursor[base + 1];
        if (base + 2 < N) a2 = cursor[base + 2];
        if (base + 3 < N) a3 = cursor[base + 3];
    }
    int ts = a0 + a1 + a2 + a3;
    s[tid] = ts;
    __syncthreads();
    for (int off = 1; off < 256; off <<= 1) {
        int xv = (tid >= off) ? s[tid - off] : 0;
        __syncthreads();
        s[tid] += xv;
        __syncthreads();
    }
    int excl_thr = s[tid] - ts;
    int total = s[255];

    if (tid == 0) {
        if (ch == 0) {
            __hip_atomic_store(&state[0], (2u << 30) | (unsigned)total,
                               __ATOMIC_RELEASE, __HIP_MEMORY_SCOPE_AGENT);
            s_run = 0;
        } else {
            __hip_atomic_store(&state[ch], (1u << 30) | (unsigned)total,
                               __ATOMIC_RELEASE, __HIP_MEMORY_SCOPE_AGENT);
            int running = 0;
            for (int j = ch - 1; j >= 0; --j) {
                unsigned st;
                do {
                    st = __hip_atomic_load(&state[j], __ATOMIC_ACQUIRE,
                                           __HIP_MEMORY_SCOPE_AGENT);
                } while ((st >> 30) == 0u);
                running += (int)(st & ((1u << 30) - 1u));
                if ((st >> 30) == 2u) break;
            }
            __hip_atomic_store(&state[ch], (2u << 30) | (unsigned)(running + total),
                               __ATOMIC_RELEASE, __HIP_MEMORY_SCOPE_AGENT);
            s_run = running;
        }
    }
    __syncthreads();
    int e = s_run + excl_thr;
    if (base < N) offsets[base] = e;
    if (base + 1 < N) offsets[base + 1] = e + a0;
    if (base + 2 < N) offsets[base + 2] = e + a0 + a1;
    if (base + 3 < N) offsets[base + 3] = e + a0 + a1 + a2;
    if (ch == nch - 1 && tid == 0) offsets[N] = E;
}

// ---------- bucket-fill CSR: sedge[offsets[col]+rank] = {row, w_raw} ----------
__global__ void k_fill4(const int4* __restrict__ row4, const int4* __restrict__ col4,
                        const float4* __restrict__ w4, const int4* __restrict__ rank4,
                        const int* __restrict__ offsets, int2* __restrict__ sedge,
                        int nthreads) {
    int t = blockIdx.x * blockDim.x + threadIdx.x;
    if (t >= nthreads) return;
    int4 r = row4[t];
    int4 c = col4[t];
    float4 w = w4[t];
    int4 k = rank4[t];
    int2 p;
    p.x = r.x; p.y = __float_as_int(w.x); sedge[offsets[c.x] + k.x] = p;
    p.x = r.y; p.y = __float_as_int(w.y); sedge[offsets[c.y] + k.y] = p;
    p.x = r.z; p.y = __float_as_int(w.z); sedge[offsets[c.z] + k.z] = p;
    p.x = r.w; p.y = __float_as_int(w.w); sedge[offsets[c.w] + k.w] = p;
}

__global__ void k_fill1(const int* __restrict__ row, const int* __restrict__ col,
                        const float* __restrict__ w, const int* __restrict__ rank,
                        const int* __restrict__ offsets, int2* __restrict__ sedge,
                        int E) {
    int e = blockIdx.x * blockDim.x + threadIdx.x;
    if (e >= E) return;
    int2 p;
    p.x = row[e];
    p.y = __float_as_int(w[e]);
    sedge[offsets[col[e]] + rank[e]] = p;
}

// ---------- FUSED: deg -> dinv, then xs1 = bf16(temp * dinv) (same wave) ----------
__global__ __launch_bounds__(256) void k_deg_scale(
        const int2* __restrict__ sedge, const int* __restrict__ offsets,
        const float* __restrict__ temp, float* __restrict__ dinv,
        bf16_t* __restrict__ xs1, int n) {
    int tid = threadIdx.x;
    int lane = tid & 63;
    int c = blockIdx.x * 4 + (tid >> 6);
    if (c >= n) return;
    int beg = offsets[c];
    int end = offsets[c + 1];
    float s = 0.0f;
    for (int j = beg + lane; j < end; j += 64) s += __int_as_float(sedge[j].y);
    for (int off = 32; off > 0; off >>= 1) s += __shfl_xor(s, off);  // all lanes get sum
    float d = 1.0f + s;
    float di = (d > 0.0f) ? rsqrtf(d) : 0.0f;
    if (lane == 0) dinv[c] = di;
    xs1[(size_t)c * DIM + lane] = f2bf(temp[(size_t)c * DIM + lane] * di);
}

// ---------- xs = bf16( (x @ W) * dinv[row] ) — layer-2 matmul ----------
__global__ __launch_bounds__(256) void k_mm(
        const float* __restrict__ x, const float* __restrict__ W,
        const float* __restrict__ dinv, bf16_t* __restrict__ xs, int n) {
    int tid = threadIdx.x;
    int lane = tid & 63;
    int waveId = blockIdx.x * 4 + (tid >> 6);
    int nWaves = gridDim.x * 4;

    float Wr[DIM];
#pragma unroll
    for (int k = 0; k < DIM; ++k) Wr[k] = W[k * DIM + lane];

    for (int r0 = waveId * 4; r0 < n; r0 += nWaves * 4) {
        if (r0 + 3 < n) {
            float x0 = x[(size_t)(r0 + 0) * DIM + lane];
            float x1 = x[(size_t)(r0 + 1) * DIM + lane];
            float x2 = x[(size_t)(r0 + 2) * DIM + lane];
            float x3 = x[(size_t)(r0 + 3) * DIM + lane];
            float a0 = 0.f, a1 = 0.f, a2 = 0.f, a3 = 0.f;
#pragma unroll
            for (int k = 0; k < DIM; ++k) {
                float w = Wr[k];
                a0 += readlane_f(x0, k) * w;
                a1 += readlane_f(x1, k) * w;
                a2 += readlane_f(x2, k) * w;
                a3 += readlane_f(x3, k) * w;
            }
            xs[(size_t)(r0 + 0) * DIM + lane] = f2bf(a0 * dinv[r0 + 0]);
            xs[(size_t)(r0 + 1) * DIM + lane] = f2bf(a1 * dinv[r0 + 1]);
            xs[(size_t)(r0 + 2) * DIM + lane] = f2bf(a2 * dinv[r0 + 2]);
            xs[(size_t)(r0 + 3) * DIM + lane] = f2bf(a3 * dinv[r0 + 3]);
        } else {
            for (int r = r0; r < n; ++r) {
                float xv = x[(size_t)r * DIM + lane];
                float a = 0.f;
#pragma unroll
                for (int k = 0; k < DIM; ++k) a += readlane_f(xv, k) * Wr[k];
                xs[(size_t)r * DIM + lane] = f2bf(a * dinv[r]);
            }
        }
    }
}

// ---------- gather (wave per node, lane = dim): xs pre-scaled by dinv[row], raw w ----------
// out[c] = 0.9*( dinv[c]*( xs[c] + sum_e w_e*xs[r_e] ) + b ) + 0.1*xprev[c]
__global__ __launch_bounds__(256) void k_gather(
        const bf16_t* __restrict__ xs, const int* __restrict__ offsets,
        const int2* __restrict__ sedge, const float* __restrict__ dinv,
        const float* __restrict__ b, const float* __restrict__ xprev,
        float* __restrict__ out, int n) {
    int lane = threadIdx.x & 63;
    int c = blockIdx.x * 4 + (threadIdx.x >> 6);
    if (c >= n) return;
    float di = dinv[c];
    float acc = bf2f(xs[(size_t)c * DIM + lane]);  // = dinv[c]*xw[c]
    int beg = offsets[c];
    int end = offsets[c + 1];
    for (int b0 = beg; b0 < end; b0 += 64) {
        int m = end - b0;
        if (m > 64) m = 64;
        int r_l = 0, w_l = 0;
        if (lane < m) {
            int2 p = sedge[b0 + lane];  // coalesced batch load
            r_l = p.x;
            w_l = p.y;
        }
        int j = 0;
        for (; j + 3 < m; j += 4) {
            int r0 = __builtin_amdgcn_readlane(r_l, j);
            int r1 = __builtin_amdgcn_readlane(r_l, j + 1);
            int r2 = __builtin_amdgcn_readlane(r_l, j + 2);
            int r3 = __builtin_amdgcn_readlane(r_l, j + 3);
            float w0 = readlane_f(__int_as_float(w_l), j);
            float w1 = readlane_f(__int_as_float(w_l), j + 1);
            float w2 = readlane_f(__int_as_float(w_l), j + 2);
            float w3 = readlane_f(__int_as_float(w_l), j + 3);
            acc += bf2f(xs[(size_t)r0 * DIM + lane]) * w0;
            acc += bf2f(xs[(size_t)r1 * DIM + lane]) * w1;
            acc += bf2f(xs[(size_t)r2 * DIM + lane]) * w2;
            acc += bf2f(xs[(size_t)r3 * DIM + lane]) * w3;
        }
        for (; j < m; ++j) {
            int r0 = __builtin_amdgcn_readlane(r_l, j);
            float w0 = readlane_f(__int_as_float(w_l), j);
            acc += bf2f(xs[(size_t)r0 * DIM + lane]) * w0;
        }
    }
    float v = (1.0f - PRESERVE) * (acc * di + b[lane])
            + PRESERVE * xprev[(size_t)c * DIM + lane];
    out[(size_t)c * DIM + lane] = v;
}

extern "C" void kernel_launch(void* const* d_in, const int* in_sizes, int n_in,
                              void* d_out, int out_size, void* d_ws, size_t ws_size,
                              hipStream_t stream) {
    const float* x  = (const float*)d_in[0];
    const int*   ei = (const int*)d_in[1];
    const float* ew = (const float*)d_in[2];
    const float* W1 = (const float*)d_in[3];
    const float* b1 = (const float*)d_in[4];
    const float* W2 = (const float*)d_in[5];
    const float* b2 = (const float*)d_in[6];

    const int N = in_sizes[0] / DIM;      // 100000
    const int E = in_sizes[2];            // 1250000
    const int* row = ei;
    const int* col = ei + E;

    const int nch = (N + SCHUNK - 1) / SCHUNK;  // ~98 scan chunks

    // workspace layout — every region size is a multiple of 16B so cursor stays
    // 16B-aligned for the scan's int4 loads.
    int2* sedge   = (int2*)d_ws;                          // E      (10.0 MB)
    float* dinv   = (float*)(sedge + E);                  // N      (0.4 MB)
    float* temp   = dinv + N;                             // N*DIM  (25.6 MB)
    bf16_t* xs1   = (bf16_t*)(temp + (size_t)N * DIM);    // N*DIM  (12.8 MB)
    bf16_t* xs2   = xs1 + (size_t)N * DIM;                // N*DIM  (12.8 MB)
    int* rank     = (int*)(xs2 + (size_t)N * DIM);        // E      (5.0 MB)
    int* cursor   = rank + E;                             // N      <- memset region
    unsigned int* state = (unsigned int*)(cursor + N);    // nch (pad to 128)
    int* offsets  = (int*)(state + 128);                  // N+1

    const int B = 256;
    const int nblkG = (N + 3) / 4;
    const int G_HM = 1536;   // 512 hist blocks + 1024 mm blocks
    const int nblkMM = 1024;

    // 1) zero cursor + scan state in one async memset (graph-capturable)
    hipMemsetAsync(cursor, 0, (size_t)(N + 128) * sizeof(int), stream);

    // 2) fused: histogram+rank || temp = x @ W1 (fp32)
    k_hist_mm<<<G_HM, B, 0, stream>>>(col, cursor, rank, E, x, W1, temp, N);

    // 3) single-launch decoupled-lookback scan: cursor -> exclusive offsets
    k_scan_lb<<<nch, B, 0, stream>>>(cursor, offsets, state, N, E, nch);

    // 4) fill CSR (no atomics), raw weights
    if ((E & 3) == 0) {
        int nt = E / 4;
        k_fill4<<<(nt + B - 1) / B, B, 0, stream>>>((const int4*)row, (const int4*)col,
                                                    (const float4*)ew, (const int4*)rank,
                                                    offsets, sedge, nt);
    } else {
        k_fill1<<<(E + B - 1) / B, B, 0, stream>>>(row, col, ew, rank, offsets, sedge, E);
    }

    // 5) fused: deg -> dinv -> xs1 = bf16(temp * dinv)
    k_deg_scale<<<nblkG, B, 0, stream>>>(sedge, offsets, temp, dinv, xs1, N);

    // 6) layer 1 gather -> temp (fp32)
    k_gather<<<nblkG, B, 0, stream>>>(xs1, offsets, sedge, dinv, b1, x, temp, N);
    // 7) layer 2 matmul: xs2 = bf16((temp @ W2) * dinv)
    k_mm<<<nblkMM, B, 0, stream>>>(temp, W2, dinv, xs2, N);
    // 8) layer 2 gather -> d_out
    k_gather<<<nblkG, B, 0, stream>>>(xs2, offsets, sedge, dinv, b2, temp,
                                      (float*)d_out, N);
}